// Round 1
// 739.508 us; speedup vs baseline: 1.2946x; 1.2946x over previous
//
#include <hip/hip_runtime.h>
#include <hip/hip_fp16.h>

#define N_USERS 100000
#define M_ITEMS 50000
#define N_NODES 150000
#define N_EDGES 6000000
#define DIM 64

#define VAL_BITS 14
#define VAL_MASK ((1u << VAL_BITS) - 1u)                  // 16383
#define VAL_SCALE 16383.0f
#define VAL_INV   (1.0f / 16383.0f)

#define N_BKT   ((N_NODES + 255) >> 8)                    // 586 buckets, 256 nodes each
#define CAP     12288                                     // LDS staging slots (mean 10240, +20 sigma)

#define P_BLK   512                                       // partition blocks (2/CU)
#define CHUNK   ((N_EDGES + P_BLK - 1) / P_BLK)           // 11719 edges per block

// ---- init: h_cur(fp16) = acc(fp32) = concat(user_emb, item_emb) ----------------
__global__ void init_kernel(const float4* __restrict__ user_emb,
                            const float4* __restrict__ item_emb,
                            ushort4* __restrict__ h_cur,
                            float4* __restrict__ acc) {
    const int n_user4 = N_USERS * DIM / 4;
    const int n_tot4  = N_NODES * DIM / 4;
    int i = blockIdx.x * blockDim.x + threadIdx.x;
    if (i < n_tot4) {
        float4 v = (i < n_user4) ? user_emb[i] : item_emb[i - n_user4];
        ushort4 hv;
        hv.x = __half_as_ushort(__float2half_rn(v.x));
        hv.y = __half_as_ushort(__float2half_rn(v.y));
        hv.z = __half_as_ushort(__float2half_rn(v.z));
        hv.w = __half_as_ushort(__float2half_rn(v.w));
        h_cur[i] = hv;
        acc[i]   = v;
    }
}

// ---- pass 1: per-(block,bucket) histogram via LDS; zero global atomics ---------
__global__ __launch_bounds__(256) void count_kernel(const int* __restrict__ dst,
                                                    int* __restrict__ cnt) {  // [P_BLK][N_BKT]
    __shared__ int hist[N_BKT];
    int p = blockIdx.x, tid = threadIdx.x;
    for (int i = tid; i < N_BKT; i += 256) hist[i] = 0;
    __syncthreads();
    int beg = p * CHUNK;
    int end = min(beg + CHUNK, N_EDGES);
    for (int e = beg + tid; e < end; e += 256) {
        int d = __builtin_nontemporal_load(&dst[e]);
        atomicAdd(&hist[d >> 8], 1);
    }
    __syncthreads();
    for (int i = tid; i < N_BKT; i += 256) cnt[p * N_BKT + i] = hist[i];
}

// ---- per-bucket exclusive scan over blocks (in place); emit bucket totals ------
__global__ __launch_bounds__(512) void colscan_kernel(int* __restrict__ cnt,     // [P_BLK][N_BKT]
                                                      int* __restrict__ totals) {// [N_BKT]
    __shared__ int lds[P_BLK];
    int b = blockIdx.x, tid = threadIdx.x;
    int v = cnt[tid * N_BKT + b];
    lds[tid] = v;
    __syncthreads();
    for (int off = 1; off < P_BLK; off <<= 1) {
        int t = (tid >= off) ? lds[tid - off] : 0;
        __syncthreads();
        lds[tid] += t;
        __syncthreads();
    }
    cnt[tid * N_BKT + b] = lds[tid] - v;                  // exclusive within bucket
    if (tid == P_BLK - 1) totals[b] = lds[P_BLK - 1];
}

// ---- exclusive scan of 586 bucket totals -> bucket_base; one block -------------
__global__ __launch_bounds__(1024) void bucket_scan_kernel(const int* __restrict__ totals,
                                                           int* __restrict__ bucket_base,
                                                           int* __restrict__ row_ptr) {
    __shared__ int lds[1024];
    int tid = threadIdx.x;
    int v = (tid < N_BKT) ? totals[tid] : 0;
    lds[tid] = v;
    __syncthreads();
    for (int off = 1; off < 1024; off <<= 1) {
        int t = (tid >= off) ? lds[tid - off] : 0;
        __syncthreads();
        lds[tid] += t;
        __syncthreads();
    }
    if (tid < N_BKT) bucket_base[tid] = lds[tid] - v;     // exclusive
    if (tid == 0) {
        bucket_base[N_BKT] = N_EDGES;
        row_ptr[N_NODES] = N_EDGES;
    }
}

// ---- pass 2: deterministic scatter into private contiguous (block,bucket) runs -
// payload = (src << 14) | round(val * 16383)   (18 + 14 = 32 bits)
__global__ __launch_bounds__(256) void scatter_kernel(const int* __restrict__ src,
                                                      const int* __restrict__ dst,
                                                      const float* __restrict__ val,
                                                      const int* __restrict__ bucket_base,
                                                      const int* __restrict__ cnt,   // relscan
                                                      uint2* __restrict__ bucketed) {
    __shared__ int lofs[N_BKT];                            // running absolute cursor
    int p = blockIdx.x, tid = threadIdx.x;
    for (int i = tid; i < N_BKT; i += 256)
        lofs[i] = bucket_base[i] + cnt[p * N_BKT + i];
    __syncthreads();
    int beg = p * CHUNK;
    int end = min(beg + CHUNK, N_EDGES);
    for (int e = beg + tid; e < end; e += 256) {
        int d = __builtin_nontemporal_load(&dst[e]);
        int s = __builtin_nontemporal_load(&src[e]);
        float w = __builtin_nontemporal_load(&val[e]);
        int b = d >> 8;
        unsigned int q = __float2uint_rn(w * VAL_SCALE);
        unsigned int payload = ((unsigned int)s << VAL_BITS) | q;
        int pos = atomicAdd(&lofs[b], 1);                  // LDS atomic only
        bucketed[pos] = make_uint2((unsigned int)d, payload);
    }
}

// ---- bucket sort: one block per bucket; LDS counting sort; coalesced CSR write -
__global__ __launch_bounds__(256) void bucket_sort_kernel(const uint2* __restrict__ bucketed,
                                                          const int* __restrict__ bucket_base,
                                                          int* __restrict__ row_ptr,
                                                          unsigned int* __restrict__ csr) {
    __shared__ unsigned int stage[CAP];    // 48 KB
    __shared__ int histo[256];
    __shared__ int cbase[256];
    __shared__ int lcur[256];

    int tid = threadIdx.x;
    int b = blockIdx.x;
    int node0 = b << 8;
    int region_base = bucket_base[b];
    int region_size = bucket_base[b + 1] - region_base;

    histo[tid] = 0;
    __syncthreads();

    // pass 1: histogram over the bucket's 256 local nodes (contiguous region read)
    for (int i = tid; i < region_size; i += 256) {
        uint2 e = bucketed[region_base + i];
        atomicAdd(&histo[e.x & 255u], 1);
    }
    __syncthreads();

    // exclusive scan of 256 counts
    int v = histo[tid];
    cbase[tid] = v;
    __syncthreads();
    for (int off = 1; off < 256; off <<= 1) {
        int t = (tid >= off) ? cbase[tid - off] : 0;
        __syncthreads();
        cbase[tid] += t;
        __syncthreads();
    }
    int excl = cbase[tid] - v;
    lcur[tid] = excl;
    int node = node0 + tid;
    if (node < N_NODES) row_ptr[node] = region_base + excl;
    __syncthreads();

    // pass 2: place payloads into LDS staging at local positions
    for (int i = tid; i < region_size; i += 256) {
        uint2 e = bucketed[region_base + i];
        int pos = atomicAdd(&lcur[e.x & 255u], 1);
        if (pos < CAP) stage[pos] = e.y;
        else           csr[region_base + pos] = e.y;       // ~never (region < CAP)
    }
    __syncthreads();

    // stream the bucket's CSR region out, fully coalesced
    int lim = min(region_size, CAP);
    for (int i = tid; i < lim; i += 256) csr[region_base + i] = stage[i];
}

// ---------------- pull SpMM: one wave per node; 8 edge-groups x 8 dim-lanes ----
__global__ __launch_bounds__(256) void spmm_pull(const int* __restrict__ row_ptr,
                                                 const unsigned int* __restrict__ csr,
                                                 const __half* __restrict__ h_in,
                                                 __half* __restrict__ h_out,
                                                 float* __restrict__ acc,
                                                 int last) {
    int lane = threadIdx.x & 63;
    int g    = lane >> 3;
    int sub  = lane & 7;
    int node = (blockIdx.x * blockDim.x + threadIdx.x) >> 6;
    if (node >= N_NODES) return;
    int beg = row_ptr[node];
    int end = row_ptr[node + 1];

    float s0 = 0.f, s1 = 0.f, s2 = 0.f, s3 = 0.f;
    float s4 = 0.f, s5 = 0.f, s6 = 0.f, s7 = 0.f;

    int j = beg + g;
    for (; j + 8 < end; j += 16) {
        unsigned int p0 = __builtin_nontemporal_load(&csr[j]);
        unsigned int p1 = __builtin_nontemporal_load(&csr[j + 8]);
        const uint4* r0p = (const uint4*)(h_in + (size_t)(p0 >> VAL_BITS) * DIM) + sub;
        const uint4* r1p = (const uint4*)(h_in + (size_t)(p1 >> VAL_BITS) * DIM) + sub;
        uint4 r0 = *r0p;
        uint4 r1 = *r1p;
        float w0 = (float)(p0 & VAL_MASK) * VAL_INV;
        float w1 = (float)(p1 & VAL_MASK) * VAL_INV;
        {
            float2 f0 = __half22float2(*(const __half2*)&r0.x);
            float2 f1 = __half22float2(*(const __half2*)&r0.y);
            float2 f2 = __half22float2(*(const __half2*)&r0.z);
            float2 f3 = __half22float2(*(const __half2*)&r0.w);
            s0 += w0 * f0.x; s1 += w0 * f0.y;
            s2 += w0 * f1.x; s3 += w0 * f1.y;
            s4 += w0 * f2.x; s5 += w0 * f2.y;
            s6 += w0 * f3.x; s7 += w0 * f3.y;
        }
        {
            float2 f0 = __half22float2(*(const __half2*)&r1.x);
            float2 f1 = __half22float2(*(const __half2*)&r1.y);
            float2 f2 = __half22float2(*(const __half2*)&r1.z);
            float2 f3 = __half22float2(*(const __half2*)&r1.w);
            s0 += w1 * f0.x; s1 += w1 * f0.y;
            s2 += w1 * f1.x; s3 += w1 * f1.y;
            s4 += w1 * f2.x; s5 += w1 * f2.y;
            s6 += w1 * f3.x; s7 += w1 * f3.y;
        }
    }
    if (j < end) {
        unsigned int p0 = __builtin_nontemporal_load(&csr[j]);
        const uint4* r0p = (const uint4*)(h_in + (size_t)(p0 >> VAL_BITS) * DIM) + sub;
        uint4 r0 = *r0p;
        float w0 = (float)(p0 & VAL_MASK) * VAL_INV;
        float2 f0 = __half22float2(*(const __half2*)&r0.x);
        float2 f1 = __half22float2(*(const __half2*)&r0.y);
        float2 f2 = __half22float2(*(const __half2*)&r0.z);
        float2 f3 = __half22float2(*(const __half2*)&r0.w);
        s0 += w0 * f0.x; s1 += w0 * f0.y;
        s2 += w0 * f1.x; s3 += w0 * f1.y;
        s4 += w0 * f2.x; s5 += w0 * f2.y;
        s6 += w0 * f3.x; s7 += w0 * f3.y;
    }

    #pragma unroll
    for (int d = 8; d < 64; d <<= 1) {
        s0 += __shfl_down(s0, d, 64);
        s1 += __shfl_down(s1, d, 64);
        s2 += __shfl_down(s2, d, 64);
        s3 += __shfl_down(s3, d, 64);
        s4 += __shfl_down(s4, d, 64);
        s5 += __shfl_down(s5, d, 64);
        s6 += __shfl_down(s6, d, 64);
        s7 += __shfl_down(s7, d, 64);
    }

    if (g == 0) {
        size_t o = (size_t)node * DIM + (size_t)sub * 8;
        float4* ap = (float4*)(acc + o);
        float4 x0 = ap[0];
        float4 x1 = ap[1];
        if (!last) {
            __half2 q0 = __floats2half2_rn(s0, s1);
            __half2 q1 = __floats2half2_rn(s2, s3);
            __half2 q2 = __floats2half2_rn(s4, s5);
            __half2 q3 = __floats2half2_rn(s6, s7);
            uint4 w4;
            w4.x = *(const unsigned int*)&q0;
            w4.y = *(const unsigned int*)&q1;
            w4.z = *(const unsigned int*)&q2;
            w4.w = *(const unsigned int*)&q3;
            *(uint4*)(h_out + o) = w4;
            x0.x += s0; x0.y += s1; x0.z += s2; x0.w += s3;
            x1.x += s4; x1.y += s5; x1.z += s6; x1.w += s7;
        } else {
            x0.x = (x0.x + s0) * 0.25f; x0.y = (x0.y + s1) * 0.25f;
            x0.z = (x0.z + s2) * 0.25f; x0.w = (x0.w + s3) * 0.25f;
            x1.x = (x1.x + s4) * 0.25f; x1.y = (x1.y + s5) * 0.25f;
            x1.z = (x1.z + s6) * 0.25f; x1.w = (x1.w + s7) * 0.25f;
        }
        ap[0] = x0;
        ap[1] = x1;
    }
}

extern "C" void kernel_launch(void* const* d_in, const int* in_sizes, int n_in,
                              void* d_out, int out_size, void* d_ws, size_t ws_size,
                              hipStream_t stream) {
    const float* user_emb = (const float*)d_in[0];
    const float* item_emb = (const float*)d_in[1];
    const int*   edge_src = (const int*)d_in[2];
    const int*   edge_dst = (const int*)d_in[3];
    const float* edge_val = (const float*)d_in[4];
    float* out = (float*)d_out;                       // acc lives here

    // ---- workspace layout (bucketed unioned with h_b: disjoint lifetimes) ----
    char* p = (char*)d_ws;
    __half* h_a = (__half*)p;                  p += (size_t)N_NODES * DIM * 2;      // 19.2 MB
    unsigned int* csr = (unsigned int*)p;      p += (size_t)N_EDGES * 4;            // 24 MB
    int* row_ptr = (int*)p;                    p += (size_t)(N_NODES + 8) * 4;      // 16B-aligned
    int* bucket_base = (int*)p;                p += (size_t)(N_BKT + 14) * 4;       // 2400 B
    int* totals = (int*)p;                     p += (size_t)(N_BKT + 14) * 4;       // 2400 B
    int* cnt = (int*)p;                        p += (size_t)P_BLK * N_BKT * 4;      // 1.2 MB
    // union region: bucketed (build phase, 48 MB) / h_b (pull phase, 19.2 MB)
    uint2*  bucketed = (uint2*)p;
    __half* h_b      = (__half*)p;

    const int n4 = N_NODES * DIM / 4;
    const int ew_blocks   = (n4 + 255) / 256;
    const int pull_blocks = (N_NODES + 3) / 4;

    // ---- build CSR: deterministic two-pass counting scatter (no global atomics) -
    init_kernel<<<ew_blocks, 256, 0, stream>>>((const float4*)user_emb,
                                               (const float4*)item_emb,
                                               (ushort4*)h_a, (float4*)out);
    count_kernel<<<P_BLK, 256, 0, stream>>>(edge_dst, cnt);
    colscan_kernel<<<N_BKT, P_BLK, 0, stream>>>(cnt, totals);
    bucket_scan_kernel<<<1, 1024, 0, stream>>>(totals, bucket_base, row_ptr);
    scatter_kernel<<<P_BLK, 256, 0, stream>>>(edge_src, edge_dst, edge_val,
                                              bucket_base, cnt, bucketed);
    bucket_sort_kernel<<<N_BKT, 256, 0, stream>>>(bucketed, bucket_base, row_ptr, csr);

    // ---- 3 pull layers, epilogues fused ----
    spmm_pull<<<pull_blocks, 256, 0, stream>>>(row_ptr, csr, h_a, h_b, out, 0);
    spmm_pull<<<pull_blocks, 256, 0, stream>>>(row_ptr, csr, h_b, h_a, out, 0);
    spmm_pull<<<pull_blocks, 256, 0, stream>>>(row_ptr, csr, h_a, h_b, out, 1);
}

// Round 2
// 706.213 us; speedup vs baseline: 1.3557x; 1.0471x over previous
//
#include <hip/hip_runtime.h>
#include <hip/hip_fp16.h>

#define N_USERS 100000
#define M_ITEMS 50000
#define N_NODES 150000
#define N_EDGES 6000000
#define DIM 64

#define VAL_BITS 14
#define VAL_MASK ((1u << VAL_BITS) - 1u)                  // 16383
#define VAL_SCALE 16383.0f
#define VAL_INV   (1.0f / 16383.0f)

#define N_BKT   ((N_NODES + 255) >> 8)                    // 586 buckets, 256 nodes each
#define CAP     12288                                     // LDS staging slots (mean 10240, +20 sigma)

#define P_BLK   512                                       // partition blocks (2/CU)
#define CHUNK   ((N_EDGES + P_BLK - 1) / P_BLK)           // 11719 edges per block

// ---- init: h_cur(fp16) = concat(user_emb, item_emb); acc deferred to layer 3 ---
__global__ void init_kernel(const float4* __restrict__ user_emb,
                            const float4* __restrict__ item_emb,
                            ushort4* __restrict__ h_cur) {
    const int n_user4 = N_USERS * DIM / 4;
    const int n_tot4  = N_NODES * DIM / 4;
    int i = blockIdx.x * blockDim.x + threadIdx.x;
    if (i < n_tot4) {
        float4 v = (i < n_user4) ? user_emb[i] : item_emb[i - n_user4];
        ushort4 hv;
        hv.x = __half_as_ushort(__float2half_rn(v.x));
        hv.y = __half_as_ushort(__float2half_rn(v.y));
        hv.z = __half_as_ushort(__float2half_rn(v.z));
        hv.w = __half_as_ushort(__float2half_rn(v.w));
        h_cur[i] = hv;
    }
}

// ---- pass 1: per-(block,bucket) histogram via LDS; zero global atomics ---------
__global__ __launch_bounds__(256) void count_kernel(const int* __restrict__ dst,
                                                    int* __restrict__ cnt) {  // [P_BLK][N_BKT]
    __shared__ int hist[N_BKT];
    int p = blockIdx.x, tid = threadIdx.x;
    for (int i = tid; i < N_BKT; i += 256) hist[i] = 0;
    __syncthreads();
    int beg = p * CHUNK;
    int end = min(beg + CHUNK, N_EDGES);
    for (int e = beg + tid; e < end; e += 256) {
        int d = __builtin_nontemporal_load(&dst[e]);
        atomicAdd(&hist[d >> 8], 1);
    }
    __syncthreads();
    for (int i = tid; i < N_BKT; i += 256) cnt[p * N_BKT + i] = hist[i];
}

// ---- per-bucket exclusive scan over blocks (in place); emit bucket totals ------
__global__ __launch_bounds__(512) void colscan_kernel(int* __restrict__ cnt,     // [P_BLK][N_BKT]
                                                      int* __restrict__ totals) {// [N_BKT]
    __shared__ int lds[P_BLK];
    int b = blockIdx.x, tid = threadIdx.x;
    int v = cnt[tid * N_BKT + b];
    lds[tid] = v;
    __syncthreads();
    for (int off = 1; off < P_BLK; off <<= 1) {
        int t = (tid >= off) ? lds[tid - off] : 0;
        __syncthreads();
        lds[tid] += t;
        __syncthreads();
    }
    cnt[tid * N_BKT + b] = lds[tid] - v;                  // exclusive within bucket
    if (tid == P_BLK - 1) totals[b] = lds[P_BLK - 1];
}

// ---- exclusive scan of 586 bucket totals -> bucket_base; one block -------------
__global__ __launch_bounds__(1024) void bucket_scan_kernel(const int* __restrict__ totals,
                                                           int* __restrict__ bucket_base,
                                                           int* __restrict__ row_ptr) {
    __shared__ int lds[1024];
    int tid = threadIdx.x;
    int v = (tid < N_BKT) ? totals[tid] : 0;
    lds[tid] = v;
    __syncthreads();
    for (int off = 1; off < 1024; off <<= 1) {
        int t = (tid >= off) ? lds[tid - off] : 0;
        __syncthreads();
        lds[tid] += t;
        __syncthreads();
    }
    if (tid < N_BKT) bucket_base[tid] = lds[tid] - v;     // exclusive
    if (tid == 0) {
        bucket_base[N_BKT] = N_EDGES;
        row_ptr[N_NODES] = N_EDGES;
    }
}

// ---- pass 2: deterministic scatter into private contiguous (block,bucket) runs -
// payload = (src << 14) | round(val * 16383)   (18 + 14 = 32 bits)
__global__ __launch_bounds__(256) void scatter_kernel(const int* __restrict__ src,
                                                      const int* __restrict__ dst,
                                                      const float* __restrict__ val,
                                                      const int* __restrict__ bucket_base,
                                                      const int* __restrict__ cnt,   // relscan
                                                      uint2* __restrict__ bucketed) {
    __shared__ int lofs[N_BKT];                            // running absolute cursor
    int p = blockIdx.x, tid = threadIdx.x;
    for (int i = tid; i < N_BKT; i += 256)
        lofs[i] = bucket_base[i] + cnt[p * N_BKT + i];
    __syncthreads();
    int beg = p * CHUNK;
    int end = min(beg + CHUNK, N_EDGES);
    for (int e = beg + tid; e < end; e += 256) {
        int d = __builtin_nontemporal_load(&dst[e]);
        int s = __builtin_nontemporal_load(&src[e]);
        float w = __builtin_nontemporal_load(&val[e]);
        int b = d >> 8;
        unsigned int q = __float2uint_rn(w * VAL_SCALE);
        unsigned int payload = ((unsigned int)s << VAL_BITS) | q;
        int pos = atomicAdd(&lofs[b], 1);                  // LDS atomic only
        bucketed[pos] = make_uint2((unsigned int)d, payload);
    }
}

// ---- bucket sort: one block per bucket; LDS counting sort; coalesced CSR write -
__global__ __launch_bounds__(256) void bucket_sort_kernel(const uint2* __restrict__ bucketed,
                                                          const int* __restrict__ bucket_base,
                                                          int* __restrict__ row_ptr,
                                                          unsigned int* __restrict__ csr) {
    __shared__ unsigned int stage[CAP];    // 48 KB
    __shared__ int histo[256];
    __shared__ int cbase[256];
    __shared__ int lcur[256];

    int tid = threadIdx.x;
    int b = blockIdx.x;
    int node0 = b << 8;
    int region_base = bucket_base[b];
    int region_size = bucket_base[b + 1] - region_base;

    histo[tid] = 0;
    __syncthreads();

    // pass 1: histogram over the bucket's 256 local nodes (contiguous region read)
    for (int i = tid; i < region_size; i += 256) {
        uint2 e = bucketed[region_base + i];
        atomicAdd(&histo[e.x & 255u], 1);
    }
    __syncthreads();

    // exclusive scan of 256 counts
    int v = histo[tid];
    cbase[tid] = v;
    __syncthreads();
    for (int off = 1; off < 256; off <<= 1) {
        int t = (tid >= off) ? cbase[tid - off] : 0;
        __syncthreads();
        cbase[tid] += t;
        __syncthreads();
    }
    int excl = cbase[tid] - v;
    lcur[tid] = excl;
    int node = node0 + tid;
    if (node < N_NODES) row_ptr[node] = region_base + excl;
    __syncthreads();

    // pass 2: place payloads into LDS staging at local positions
    for (int i = tid; i < region_size; i += 256) {
        uint2 e = bucketed[region_base + i];
        int pos = atomicAdd(&lcur[e.x & 255u], 1);
        if (pos < CAP) stage[pos] = e.y;
        else           csr[region_base + pos] = e.y;       // ~never (region < CAP)
    }
    __syncthreads();

    // stream the bucket's CSR region out, fully coalesced
    int lim = min(region_size, CAP);
    for (int i = tid; i < lim; i += 256) csr[region_base + i] = stage[i];
}

// ---------------- pull SpMM: one wave per node; 8 edge-groups x 8 dim-lanes ----
// Non-last layers: write fp16 h_out only.  Last layer: out = 0.25*(emb+h1+h2+s3).
#define GATHER(P, R) uint4 R = *((const uint4*)(h_in + (size_t)((P) >> VAL_BITS) * DIM) + sub);
#define ACCUM(P, R) { \
    float w = (float)((P) & VAL_MASK) * VAL_INV; \
    float2 f0 = __half22float2(*(const __half2*)&R.x); \
    float2 f1 = __half22float2(*(const __half2*)&R.y); \
    float2 f2 = __half22float2(*(const __half2*)&R.z); \
    float2 f3 = __half22float2(*(const __half2*)&R.w); \
    s0 += w * f0.x; s1 += w * f0.y; \
    s2 += w * f1.x; s3 += w * f1.y; \
    s4 += w * f2.x; s5 += w * f2.y; \
    s6 += w * f3.x; s7 += w * f3.y; }

__global__ __launch_bounds__(256) void spmm_pull(const int* __restrict__ row_ptr,
                                                 const unsigned int* __restrict__ csr,
                                                 const __half* __restrict__ h_in,
                                                 __half* __restrict__ h_out,
                                                 const __half* __restrict__ h1,
                                                 const float* __restrict__ user_emb,
                                                 const float* __restrict__ item_emb,
                                                 float* __restrict__ out,
                                                 int last) {
    int lane = threadIdx.x & 63;
    int g    = lane >> 3;
    int sub  = lane & 7;
    int node = (blockIdx.x * blockDim.x + threadIdx.x) >> 6;
    if (node >= N_NODES) return;
    int beg = row_ptr[node];
    int end = row_ptr[node + 1];

    float s0 = 0.f, s1 = 0.f, s2 = 0.f, s3 = 0.f;
    float s4 = 0.f, s5 = 0.f, s6 = 0.f, s7 = 0.f;

    int j = beg + g;
    // 4-deep: 4 independent gathers (4 KB/wave) in flight
    for (; j + 24 < end; j += 32) {
        unsigned int p0 = __builtin_nontemporal_load(&csr[j]);
        unsigned int p1 = __builtin_nontemporal_load(&csr[j + 8]);
        unsigned int p2 = __builtin_nontemporal_load(&csr[j + 16]);
        unsigned int p3 = __builtin_nontemporal_load(&csr[j + 24]);
        GATHER(p0, r0) GATHER(p1, r1) GATHER(p2, r2) GATHER(p3, r3)
        ACCUM(p0, r0) ACCUM(p1, r1) ACCUM(p2, r2) ACCUM(p3, r3)
    }
    for (; j + 8 < end; j += 16) {
        unsigned int p0 = __builtin_nontemporal_load(&csr[j]);
        unsigned int p1 = __builtin_nontemporal_load(&csr[j + 8]);
        GATHER(p0, r0) GATHER(p1, r1)
        ACCUM(p0, r0) ACCUM(p1, r1)
    }
    if (j < end) {
        unsigned int p0 = __builtin_nontemporal_load(&csr[j]);
        GATHER(p0, r0)
        ACCUM(p0, r0)
    }

    #pragma unroll
    for (int d = 8; d < 64; d <<= 1) {
        s0 += __shfl_down(s0, d, 64);
        s1 += __shfl_down(s1, d, 64);
        s2 += __shfl_down(s2, d, 64);
        s3 += __shfl_down(s3, d, 64);
        s4 += __shfl_down(s4, d, 64);
        s5 += __shfl_down(s5, d, 64);
        s6 += __shfl_down(s6, d, 64);
        s7 += __shfl_down(s7, d, 64);
    }

    if (g == 0) {
        size_t o = (size_t)node * DIM + (size_t)sub * 8;   // element offset
        if (!last) {
            __half2 q0 = __floats2half2_rn(s0, s1);
            __half2 q1 = __floats2half2_rn(s2, s3);
            __half2 q2 = __floats2half2_rn(s4, s5);
            __half2 q3 = __floats2half2_rn(s6, s7);
            uint4 w4;
            w4.x = *(const unsigned int*)&q0;
            w4.y = *(const unsigned int*)&q1;
            w4.z = *(const unsigned int*)&q2;
            w4.w = *(const unsigned int*)&q3;
            *(uint4*)(h_out + o) = w4;
        } else {
            // h1 row (fp16), h2 row (= h_in own row, fp16), emb row (fp32 inputs)
            uint4 a1 = *(const uint4*)(h1 + o);
            uint4 a2 = *(const uint4*)(h_in + o);
            float2 b0 = __half22float2(*(const __half2*)&a1.x);
            float2 b1 = __half22float2(*(const __half2*)&a1.y);
            float2 b2 = __half22float2(*(const __half2*)&a1.z);
            float2 b3 = __half22float2(*(const __half2*)&a1.w);
            float2 c0 = __half22float2(*(const __half2*)&a2.x);
            float2 c1 = __half22float2(*(const __half2*)&a2.y);
            float2 c2 = __half22float2(*(const __half2*)&a2.z);
            float2 c3 = __half22float2(*(const __half2*)&a2.w);
            float4 e0, e1;
            if (node < N_USERS) {
                const float4* up = (const float4*)(user_emb) + (o >> 2);
                e0 = up[0]; e1 = up[1];
            } else {
                size_t oo = o - (size_t)N_USERS * DIM;
                const float4* ip = (const float4*)(item_emb) + (oo >> 2);
                e0 = ip[0]; e1 = ip[1];
            }
            float4 x0, x1;
            x0.x = (e0.x + b0.x + c0.x + s0) * 0.25f;
            x0.y = (e0.y + b0.y + c0.y + s1) * 0.25f;
            x0.z = (e0.z + b1.x + c1.x + s2) * 0.25f;
            x0.w = (e0.w + b1.y + c1.y + s3) * 0.25f;
            x1.x = (e1.x + b2.x + c2.x + s4) * 0.25f;
            x1.y = (e1.y + b2.y + c2.y + s5) * 0.25f;
            x1.z = (e1.z + b3.x + c3.x + s6) * 0.25f;
            x1.w = (e1.w + b3.y + c3.y + s7) * 0.25f;
            float4* op = (float4*)(out + o);
            op[0] = x0;
            op[1] = x1;
        }
    }
}

extern "C" void kernel_launch(void* const* d_in, const int* in_sizes, int n_in,
                              void* d_out, int out_size, void* d_ws, size_t ws_size,
                              hipStream_t stream) {
    const float* user_emb = (const float*)d_in[0];
    const float* item_emb = (const float*)d_in[1];
    const int*   edge_src = (const int*)d_in[2];
    const int*   edge_dst = (const int*)d_in[3];
    const float* edge_val = (const float*)d_in[4];
    float* out = (float*)d_out;

    // ---- workspace layout (bucketed unioned with h_b: disjoint lifetimes) ----
    char* p = (char*)d_ws;
    __half* h_a = (__half*)p;                  p += (size_t)N_NODES * DIM * 2;      // 19.2 MB
    unsigned int* csr = (unsigned int*)p;      p += (size_t)N_EDGES * 4;            // 24 MB
    int* row_ptr = (int*)p;                    p += (size_t)(N_NODES + 8) * 4;      // 16B-aligned
    int* bucket_base = (int*)p;                p += (size_t)(N_BKT + 14) * 4;       // 2400 B
    int* totals = (int*)p;                     p += (size_t)(N_BKT + 14) * 4;       // 2400 B
    int* cnt = (int*)p;                        p += (size_t)P_BLK * N_BKT * 4;      // 1.2 MB
    // union region: bucketed (build phase, 48 MB) / h_b (pull phase, 19.2 MB)
    uint2*  bucketed = (uint2*)p;
    __half* h_b      = (__half*)p;

    const int n4 = N_NODES * DIM / 4;
    const int ew_blocks   = (n4 + 255) / 256;
    const int pull_blocks = (N_NODES + 3) / 4;

    // ---- build CSR: deterministic two-pass counting scatter (no global atomics) -
    init_kernel<<<ew_blocks, 256, 0, stream>>>((const float4*)user_emb,
                                               (const float4*)item_emb,
                                               (ushort4*)h_a);
    count_kernel<<<P_BLK, 256, 0, stream>>>(edge_dst, cnt);
    colscan_kernel<<<N_BKT, P_BLK, 0, stream>>>(cnt, totals);
    bucket_scan_kernel<<<1, 1024, 0, stream>>>(totals, bucket_base, row_ptr);
    scatter_kernel<<<P_BLK, 256, 0, stream>>>(edge_src, edge_dst, edge_val,
                                              bucket_base, cnt, bucketed);
    bucket_sort_kernel<<<N_BKT, 256, 0, stream>>>(bucketed, bucket_base, row_ptr, csr);

    // ---- 3 pull layers; acc fully deferred into layer-3 epilogue ----
    // L1: h_a(h0) -> h_b(h1);  L2: h_b(h1) -> h_a(h2);  L3: h_a(h2) -> out
    spmm_pull<<<pull_blocks, 256, 0, stream>>>(row_ptr, csr, h_a, h_b, h_b,
                                               user_emb, item_emb, out, 0);
    spmm_pull<<<pull_blocks, 256, 0, stream>>>(row_ptr, csr, h_b, h_a, h_b,
                                               user_emb, item_emb, out, 0);
    spmm_pull<<<pull_blocks, 256, 0, stream>>>(row_ptr, csr, h_a, h_b, h_b,
                                               user_emb, item_emb, out, 1);
}